// Round 7
// baseline (316.856 us; speedup 1.0000x reference)
//
#include <hip/hip_runtime.h>
#include <stdint.h>

// LIF spike encoder — two-phase, bit-exact fp32.
//   R4 fused: 320 us. R5 split (dense 243 us, occupancy-starved).
//   R6 dense re-tile: 154 us — L2-latency-bound (VALUBusy 19%, 2 waves/SIMD,
//     ~8 loads in flight). Total 209.6 with ~52 us in phase B = 268 MB output
//     write drain (~6 TB/s floor; R5's "5 us" was masked by the slow dense).
//   R7 (this): dense with O=2 outputs/thread (float2 W), 512-thread blocks,
//     BM=8 x BN=128, grid m-fast (consecutive blocks share W cols in L2),
//     unroll-16 k (16 loads in flight/wave, 4 waves/SIMD), wave-uniform
//     ds_read_b128 for x. Chain stays single-register ascending-k fmaf.
// Bit-exactness: every output element is ONE register accumulated by fmaf
// over k=0..2047 ascending -> identical chain to all passing rounds.

#define BATCHSZ 256
#define NU      2048
#define TSTEPS  128
#define BLK     1024
#define NWAVES  (BLK / 64)

// ---------------- Phase A: dense GEMM (t=1), bit-exact chain ----------------
#define A_BM 8
#define A_BN 128
#define A_THR 512

__global__ __launch_bounds__(A_THR) void lif_dense_v1(
    const float* __restrict__ x,
    const float* __restrict__ W,
    float* __restrict__ ws)
{
    __shared__ float s_x[A_BM][NU];          // 64 KB: the block's 8 x-rows

    const int tid = threadIdx.x;
    const int m0  = blockIdx.x * A_BM;       // m-tile fast: L2 W-slice sharing
    const int n0  = blockIdx.y * A_BN;

    // ---- stage 8 x-rows: wave w stages row w, 8 coalesced float4 per lane
    {
        const int w = tid >> 6;              // 0..7
        const int l = tid & 63;              // 0..63
        const float* xr = x + (size_t)(m0 + w) * NU;
        float*       dr = &s_x[w][0];
        #pragma unroll
        for (int it = 0; it < 8; ++it) {
            int col = it * 256 + l * 4;
            *(float4*)&dr[col] = *(const float4*)&xr[col];
        }
    }
    __syncthreads();

    const int mg = tid >> 6;                 // row 0..7 (wave-uniform)
    const int cg = tid & 63;                 // col pair 0..63
    const int n  = n0 + cg * 2;

    const float* xr = &s_x[mg][0];
    const float* wp = W + n;

    float2 acc; acc.x = 0.0f; acc.y = 0.0f;

    for (int k0 = 0; k0 < NU; k0 += 16) {
        // x broadcast reads: wave-uniform b128 (0 conflicts)
        float4 x0 = *(const float4*)&xr[k0 + 0];
        float4 x1 = *(const float4*)&xr[k0 + 4];
        float4 x2 = *(const float4*)&xr[k0 + 8];
        float4 x3 = *(const float4*)&xr[k0 + 12];
        float xs[16];
        xs[ 0] = x0.x; xs[ 1] = x0.y; xs[ 2] = x0.z; xs[ 3] = x0.w;
        xs[ 4] = x1.x; xs[ 5] = x1.y; xs[ 6] = x1.z; xs[ 7] = x1.w;
        xs[ 8] = x2.x; xs[ 9] = x2.y; xs[10] = x2.z; xs[11] = x2.w;
        xs[12] = x3.x; xs[13] = x3.y; xs[14] = x3.z; xs[15] = x3.w;

        // 16 independent W loads in flight (coalesced 512 B/wave each)
        float2 wv[16];
        #pragma unroll
        for (int j = 0; j < 16; ++j)
            wv[j] = *(const float2*)(wp + (size_t)(k0 + j) * NU);

        // sequential accumulation, k ascending (bit-exact chain)
        #pragma unroll
        for (int j = 0; j < 16; ++j) {
            acc.x = __builtin_fmaf(xs[j], wv[j].x, acc.x);
            acc.y = __builtin_fmaf(xs[j], wv[j].y, acc.y);
        }
    }

    *(float2*)&ws[(size_t)(m0 + mg) * NU + n] = acc;
}

// ---------------- Phase B: recurrence from t=2 (unchanged, proven) ---------
__global__ __launch_bounds__(BLK) void lif_recurrence(
    const float* __restrict__ x,
    const float* __restrict__ W,
    const float* __restrict__ V1,
    float* __restrict__ out)
{
    const int b    = blockIdx.x;
    const int tid  = threadIdx.x;
    const int lane = tid & 63;
    const int wid  = tid >> 6;

    __shared__ int           s_idx[NU];      // spiking row offsets (k*NU)
    __shared__ unsigned char s_flag[NU];
    __shared__ int           s_wsum[NWAVES];
    __shared__ int           s_cnt;

    const int n0 = tid;
    const int n1 = tid + BLK;

    float* outb = out + (size_t)b * TSTEPS * NU;   // (B, T, N)

    float V0, V1r;
    int   z0, z1;
    {
        float x0 = x[(size_t)b * NU + n0];
        float x1 = x[(size_t)b * NU + n1];
        outb[n0] = x0;
        outb[n1] = x1;
        V0  = V1[(size_t)b * NU + n0];
        V1r = V1[(size_t)b * NU + n1];
        z0 = V0  > 1.0f;
        z1 = V1r > 1.0f;
        float* f1 = outb + NU;
        f1[n0] = z0 ? 1.0f : 0.0f;
        f1[n1] = z1 ? 1.0f : 0.0f;
        s_flag[n0] = (unsigned char)z0;
        s_flag[n1] = (unsigned char)z1;
    }
    __syncthreads();

    for (int t = 2; t < TSTEPS; ++t) {
        int f0 = s_flag[2 * tid];
        int f1 = s_flag[2 * tid + 1];
        int c  = f0 + f1;
        int v  = c;
        #pragma unroll
        for (int d = 1; d < 64; d <<= 1) {
            int o = __shfl_up(v, d);
            if (lane >= d) v += o;
        }
        if (lane == 63) s_wsum[wid] = v;
        __syncthreads();
        int base = 0;
        #pragma unroll
        for (int w = 0; w < NWAVES; ++w) base += (w < wid) ? s_wsum[w] : 0;
        int off = base + v - c;                   // exclusive prefix
        if (f0) s_idx[off++] = (2 * tid) * NU;
        if (f1) s_idx[off]   = (2 * tid + 1) * NU;
        if (tid == BLK - 1) s_cnt = base + v;
        __syncthreads();

        int cnt = s_cnt;
        if (cnt == 0) {
            size_t  elems  = (size_t)(TSTEPS - t) * NU;
            float4* p      = (float4*)(outb + (size_t)t * NU);
            int     chunks = (int)(elems / 4);
            float4  zz; zz.x = zz.y = zz.z = zz.w = 0.0f;
            for (int i = tid; i < chunks; i += BLK) p[i] = zz;
            return;
        }

        float I0 = 0.0f, I1 = 0.0f;
        const float* Wc = W + tid;
        int i = 0;
        for (; i + 4 <= cnt; i += 4) {
            const float* r0 = Wc + s_idx[i];
            const float* r1 = Wc + s_idx[i + 1];
            const float* r2 = Wc + s_idx[i + 2];
            const float* r3 = Wc + s_idx[i + 3];
            float a0 = r0[0], b0 = r0[BLK];
            float a1 = r1[0], b1 = r1[BLK];
            float a2 = r2[0], b2 = r2[BLK];
            float a3 = r3[0], b3 = r3[BLK];
            I0 += a0; I0 += a1; I0 += a2; I0 += a3;   // order preserved
            I1 += b0; I1 += b1; I1 += b2; I1 += b3;
        }
        for (; i < cnt; ++i) {
            const float* r = Wc + s_idx[i];
            I0 += r[0];
            I1 += r[BLK];
        }

        float d0 = 0.90483741803595952f * V0;     // one rounding
        float d1 = 0.90483741803595952f * V1r;
        asm volatile("" : "+v"(d0), "+v"(d1));    // forbid fma-contraction
        float nv0 = (z0 ? 0.0f : d0) + I0;        // one rounding
        float nv1 = (z1 ? 0.0f : d1) + I1;
        V0 = nv0; V1r = nv1;
        z0 = nv0 > 1.0f;
        z1 = nv1 > 1.0f;

        float* po = outb + (size_t)t * NU;
        po[n0] = z0 ? 1.0f : 0.0f;
        po[n1] = z1 ? 1.0f : 0.0f;
        s_flag[n0] = (unsigned char)z0;
        s_flag[n1] = (unsigned char)z1;
        __syncthreads();
    }
}

// ---------------- Fallback: round-4 fused kernel (proven) ------------------
__global__ __launch_bounds__(BLK) void lif_fused(
    const float* __restrict__ x,
    const float* __restrict__ W,
    float* __restrict__ out)
{
    const int b    = blockIdx.x;
    const int tid  = threadIdx.x;
    const int lane = tid & 63;
    const int wid  = tid >> 6;

    __shared__ float         s_x[NU];
    __shared__ int           s_idx[NU];
    __shared__ unsigned char s_flag[NU];
    __shared__ int           s_wsum[NWAVES];
    __shared__ int           s_cnt;

    const int n0 = tid;
    const int n1 = tid + BLK;
    float* outb = out + (size_t)b * TSTEPS * NU;

    {
        float x0 = x[(size_t)b * NU + n0];
        float x1 = x[(size_t)b * NU + n1];
        s_x[n0] = x0; s_x[n1] = x1;
        outb[n0] = x0; outb[n1] = x1;
    }
    __syncthreads();

    float I0 = 0.0f, I1 = 0.0f;
    {
        const float* Wc = W + tid;
        #pragma unroll 8
        for (int k = 0; k < NU; ++k) {
            float xk = s_x[k];
            const float* wr = Wc + (size_t)k * NU;
            I0 = __builtin_fmaf(xk, wr[0],   I0);
            I1 = __builtin_fmaf(xk, wr[BLK], I1);
        }
    }

    float V0 = 0.0f, V1 = 0.0f;
    int   z0 = 0,    z1 = 0;

    for (int t = 1; t < TSTEPS; ++t) {
        if (t >= 2) {
            int f0 = s_flag[2 * tid];
            int f1 = s_flag[2 * tid + 1];
            int c  = f0 + f1;
            int v  = c;
            #pragma unroll
            for (int d = 1; d < 64; d <<= 1) {
                int o = __shfl_up(v, d);
                if (lane >= d) v += o;
            }
            if (lane == 63) s_wsum[wid] = v;
            __syncthreads();
            int base = 0;
            #pragma unroll
            for (int w = 0; w < NWAVES; ++w) base += (w < wid) ? s_wsum[w] : 0;
            int off = base + v - c;
            if (f0) s_idx[off++] = 2 * tid;
            if (f1) s_idx[off]   = 2 * tid + 1;
            if (tid == BLK - 1) s_cnt = base + v;
            __syncthreads();

            int cnt = s_cnt;
            if (cnt == 0) {
                size_t  elems  = (size_t)(TSTEPS - t) * NU;
                float4* p      = (float4*)(outb + (size_t)t * NU);
                int     chunks = (int)(elems / 4);
                float4  zz; zz.x = zz.y = zz.z = zz.w = 0.0f;
                for (int i = tid; i < chunks; i += BLK) p[i] = zz;
                return;
            }

            I0 = 0.0f; I1 = 0.0f;
            const float* Wc = W + tid;
            int i = 0;
            for (; i + 2 <= cnt; i += 2) {
                const float* r0 = Wc + (size_t)s_idx[i]     * NU;
                const float* r1 = Wc + (size_t)s_idx[i + 1] * NU;
                float a0 = r0[0], b0 = r0[BLK];
                float a1 = r1[0], b1 = r1[BLK];
                I0 += a0; I0 += a1;
                I1 += b0; I1 += b1;
            }
            for (; i < cnt; ++i) {
                const float* r = Wc + (size_t)s_idx[i] * NU;
                I0 += r[0];
                I1 += r[BLK];
            }
        }

        float d0 = 0.90483741803595952f * V0;
        float d1 = 0.90483741803595952f * V1;
        asm volatile("" : "+v"(d0), "+v"(d1));
        float nv0 = (z0 ? 0.0f : d0) + I0;
        float nv1 = (z1 ? 0.0f : d1) + I1;
        V0 = nv0; V1 = nv1;
        z0 = nv0 > 1.0f;
        z1 = nv1 > 1.0f;

        float* po = outb + (size_t)t * NU;
        po[n0] = z0 ? 1.0f : 0.0f;
        po[n1] = z1 ? 1.0f : 0.0f;
        s_flag[n0] = (unsigned char)z0;
        s_flag[n1] = (unsigned char)z1;
        __syncthreads();
    }
}

extern "C" void kernel_launch(void* const* d_in, const int* in_sizes, int n_in,
                              void* d_out, int out_size, void* d_ws, size_t ws_size,
                              hipStream_t stream) {
    const float* x = (const float*)d_in[0];   // (256, 2048) fp32
    const float* W = (const float*)d_in[1];   // (2048, 2048) fp32
    if (n_in >= 2 && in_sizes[0] == NU * NU && in_sizes[1] == BATCHSZ * NU) {
        const float* t = x; x = W; W = t;     // defensive input-order swap
    }
    float* out = (float*)d_out;               // (B, T, N) fp32

    const size_t need = (size_t)BATCHSZ * NU * sizeof(float);   // 2 MB
    if (ws_size >= need) {
        float* V1 = (float*)d_ws;
        hipLaunchKernelGGL(lif_dense_v1,
                           dim3(BATCHSZ / A_BM, NU / A_BN), dim3(A_THR), 0, stream,
                           x, W, V1);
        hipLaunchKernelGGL(lif_recurrence,
                           dim3(BATCHSZ), dim3(BLK), 0, stream,
                           x, W, V1, out);
    } else {
        hipLaunchKernelGGL(lif_fused, dim3(BATCHSZ), dim3(BLK), 0, stream,
                           x, W, out);
    }
}